// Round 4
// baseline (270.899 us; speedup 1.0000x reference)
//
#include <hip/hip_runtime.h>
#include <math.h>

#define T_SEQ 2048
#define D_MODEL 2048
#define HEAD_DIM 64
#define N_HEADS 32
#define N_KV 8

using short8 = __attribute__((ext_vector_type(8))) short;
using f32x4  = __attribute__((ext_vector_type(4))) float;

#define MFMA16(a, b, c) __builtin_amdgcn_mfma_f32_16x16x32_bf16(a, b, c, 0, 0, 0)

__device__ __forceinline__ unsigned short f2bf(float f) {
    unsigned int u = __builtin_bit_cast(unsigned int, f);
    u += 0x7fff + ((u >> 16) & 1);
    return (unsigned short)(u >> 16);
}
__device__ __forceinline__ float bf2f(unsigned short h) {
    unsigned int u = ((unsigned int)h) << 16;
    return __builtin_bit_cast(float, u);
}
__device__ __forceinline__ void gld_lds16(const ushort* g, ushort* l) {
    __builtin_amdgcn_global_load_lds((const __attribute__((address_space(1))) void*)g,
                                     (__attribute__((address_space(3))) void*)l, 16, 0, 0);
}

// ---------------------------------------------------------------------------
// RoPE tables (llama3 scaling), fp32, transposed [i][T]
// ---------------------------------------------------------------------------
__global__ void rope_tables_kernel(float* __restrict__ cosT, float* __restrict__ sinT,
                                   const int* __restrict__ start_pos, int T) {
    int t = blockIdx.x;
    int i = threadIdx.x;  // 0..31
    float pos = (float)(start_pos[0] + t);
    float expo = (float)i / 32.0f;
    float inv_freq = 1.0f / powf(500000.0f, expo);
    const float two_pi = 6.283185307179586f;
    float wavelen = two_pi / inv_freq;
    const float low_wl = 8192.0f;
    const float high_wl = 2048.0f;
    float inv;
    if (wavelen > low_wl) {
        inv = inv_freq / 32.0f;
    } else if (wavelen < high_wl) {
        inv = inv_freq;
    } else {
        float smooth = (8192.0f / wavelen - 1.0f) / 3.0f;
        inv = (1.0f - smooth) * (inv_freq / 32.0f) + smooth * inv_freq;
    }
    float ang = pos * inv;
    cosT[i * T + t] = cosf(ang);
    sinT[i * T + t] = sinf(ang);
}

// ---------------------------------------------------------------------------
// One cast kernel for all five fp32->bf16 conversions (float4 granules)
// ---------------------------------------------------------------------------
__global__ __launch_bounds__(256) void cast_all_kernel(
    const float* __restrict__ x, const float* __restrict__ wq,
    const float* __restrict__ wk, const float* __restrict__ wv,
    const float* __restrict__ wo,
    ushort* __restrict__ xb, ushort* __restrict__ wqb,
    ushort* __restrict__ wkb, ushort* __restrict__ wvb, ushort* __restrict__ wob) {
    int i = blockIdx.x * 256 + threadIdx.x;
    const float* src; ushort* dst; int off;
    if (i < 1048576)      { src = x;  dst = xb;  off = i; }
    else if (i < 2097152) { src = wq; dst = wqb; off = i - 1048576; }
    else if (i < 2359296) { src = wk; dst = wkb; off = i - 2097152; }
    else if (i < 2621440) { src = wv; dst = wvb; off = i - 2359296; }
    else                  { src = wo; dst = wob; off = i - 2621440; }
    float4 v = ((const float4*)src)[off];
    ushort4 o;
    o.x = f2bf(v.x); o.y = f2bf(v.y); o.z = f2bf(v.z); o.w = f2bf(v.w);
    ((ushort4*)dst)[off] = o;
}

// ---------------------------------------------------------------------------
// Fused QKV GEMM + RoPE epilogue. 128x128 tile, BK=32, double-buffered LDS
// with XOR-swizzled chunks (p = c ^ (row&3)), single barrier per K-step.
// grid.y: 0..15 Q (rope), 16..19 K (rope), 20..23 V (transposed, no rope).
// ---------------------------------------------------------------------------
__global__ __launch_bounds__(256) void gemm_qkv(
    const ushort* __restrict__ X, const ushort* __restrict__ Wqb,
    const ushort* __restrict__ Wkb, const ushort* __restrict__ Wvb,
    ushort* __restrict__ Qo, ushort* __restrict__ Ko, ushort* __restrict__ Vto,
    const float* __restrict__ cosT, const float* __restrict__ sinT,
    int T, int D) {
    __shared__ __align__(16) ushort As[2][4096];
    __shared__ __align__(16) ushort Bs[2][4096];
    const int tid = threadIdx.x;
    const int w = tid >> 6, l = tid & 63;
    const int m0 = blockIdx.x * 128;
    const int n0g = blockIdx.y * 128;

    const ushort* B;
    ushort* Cout;
    int n0, doRope;
    if (n0g < 2048)      { B = Wqb + (size_t)n0g * D;          Cout = Qo;  n0 = n0g;        doRope = 1; }
    else if (n0g < 2560) { B = Wkb + (size_t)(n0g - 2048) * D; Cout = Ko;  n0 = n0g - 2048; doRope = 1; }
    else                 { B = Wvb + (size_t)(n0g - 2560) * D; Cout = Vto; n0 = n0g - 2560; doRope = 0; }

    const int wm = (w >> 1) * 64, wn = (w & 1) * 64;
    const int lr = l & 15;
    const int quad = l >> 4;

    f32x4 zero = {0.f, 0.f, 0.f, 0.f};
    f32x4 acc[4][4];
#pragma unroll
    for (int i = 0; i < 4; ++i)
#pragma unroll
        for (int j = 0; j < 4; ++j) acc[i][j] = zero;

    // staging: rows of 64B = 4 chunks of 16B; swizzle p = c ^ (row&3)
    const int srow = l >> 2;                       // 0..15
    const int scg  = ((l & 3) ^ (srow & 3)) * 8;   // global chunk (ushorts)
    const int si0 = 2 * w, si1 = 2 * w + 1;
    const ushort* Ag0 = X + (size_t)(m0 + 16 * si0 + srow) * D + scg;
    const ushort* Ag1 = X + (size_t)(m0 + 16 * si1 + srow) * D + scg;
    const ushort* Bg0 = B + (size_t)(16 * si0 + srow) * D + scg;
    const ushort* Bg1 = B + (size_t)(16 * si1 + srow) * D + scg;

    gld_lds16(Ag0, &As[0][si0 * 512]);
    gld_lds16(Ag1, &As[0][si1 * 512]);
    gld_lds16(Bg0, &Bs[0][si0 * 512]);
    gld_lds16(Bg1, &Bs[0][si1 * 512]);

    const int rsw = (quad ^ (lr & 3)) * 8;  // swizzled read chunk offset
    for (int k0 = 0; k0 < D; k0 += 32) {
        const int b = (k0 >> 5) & 1;
        __syncthreads();
        if (k0 + 32 < D) {
            gld_lds16(Ag0 + k0 + 32, &As[b ^ 1][si0 * 512]);
            gld_lds16(Ag1 + k0 + 32, &As[b ^ 1][si1 * 512]);
            gld_lds16(Bg0 + k0 + 32, &Bs[b ^ 1][si0 * 512]);
            gld_lds16(Bg1 + k0 + 32, &Bs[b ^ 1][si1 * 512]);
        }
        short8 af[4], bf[4];
#pragma unroll
        for (int i = 0; i < 4; ++i) af[i] = *(const short8*)&As[b][(wm + i * 16 + lr) * 32 + rsw];
#pragma unroll
        for (int j = 0; j < 4; ++j) bf[j] = *(const short8*)&Bs[b][(wn + j * 16 + lr) * 32 + rsw];
#pragma unroll
        for (int i = 0; i < 4; ++i)
#pragma unroll
            for (int j = 0; j < 4; ++j)
                acc[i][j] = MFMA16(af[i], bf[j], acc[i][j]);
    }

    const int mbase = m0 + wm + quad * 4;
    if (doRope) {
#pragma unroll
        for (int i = 0; i < 4; ++i) {
            int trow = mbase + i * 16;
#pragma unroll
            for (int j = 0; j < 2; ++j) {
                int i1 = lr + j * 16;
                float4 c4 = *(const float4*)&cosT[(size_t)i1 * T + trow];
                float4 s4 = *(const float4*)&sinT[(size_t)i1 * T + trow];
                int n1 = n0 + wn + lr + j * 16;
                int n2 = n1 + 32;
                size_t b1 = (size_t)(n1 >> 6) * ((size_t)T * 64) + (size_t)(n1 & 63);
                size_t b2 = (size_t)(n2 >> 6) * ((size_t)T * 64) + (size_t)(n2 & 63);
                float cs[4] = {c4.x, c4.y, c4.z, c4.w};
                float sn[4] = {s4.x, s4.y, s4.z, s4.w};
#pragma unroll
                for (int r = 0; r < 4; ++r) {
                    float x1 = acc[i][j][r], x2 = acc[i][j + 2][r];
                    Cout[b1 + (size_t)(trow + r) * 64] = f2bf(x1 * cs[r] - x2 * sn[r]);
                    Cout[b2 + (size_t)(trow + r) * 64] = f2bf(x2 * cs[r] + x1 * sn[r]);
                }
            }
        }
    } else {
#pragma unroll
        for (int i = 0; i < 4; ++i)
#pragma unroll
            for (int j = 0; j < 4; ++j) {
                int n = n0 + wn + lr + j * 16;
                int m = mbase + i * 16;
                ushort4 o;
                o.x = f2bf(acc[i][j][0]); o.y = f2bf(acc[i][j][1]);
                o.z = f2bf(acc[i][j][2]); o.w = f2bf(acc[i][j][3]);
                *(ushort4*)&Vto[(size_t)n * T + m] = o;
            }
    }
}

// ---------------------------------------------------------------------------
// Output projection GEMM (C fp32), same dbuf+swizzle core
// ---------------------------------------------------------------------------
__global__ __launch_bounds__(256) void gemm_bt_f32(const ushort* __restrict__ A,
                                                   const ushort* __restrict__ B,
                                                   float* __restrict__ C,
                                                   int M, int N, int K) {
    __shared__ __align__(16) ushort As[2][4096];
    __shared__ __align__(16) ushort Bs[2][4096];
    const int tid = threadIdx.x;
    const int w = tid >> 6, l = tid & 63;
    const int m0 = blockIdx.x * 128, n0 = blockIdx.y * 128;
    const int wm = (w >> 1) * 64, wn = (w & 1) * 64;
    const int lr = l & 15;
    const int quad = l >> 4;

    f32x4 zero = {0.f, 0.f, 0.f, 0.f};
    f32x4 acc[4][4];
#pragma unroll
    for (int i = 0; i < 4; ++i)
#pragma unroll
        for (int j = 0; j < 4; ++j) acc[i][j] = zero;

    const int srow = l >> 2;
    const int scg  = ((l & 3) ^ (srow & 3)) * 8;
    const int si0 = 2 * w, si1 = 2 * w + 1;
    const ushort* Ag0 = A + (size_t)(m0 + 16 * si0 + srow) * K + scg;
    const ushort* Ag1 = A + (size_t)(m0 + 16 * si1 + srow) * K + scg;
    const ushort* Bg0 = B + (size_t)(n0 + 16 * si0 + srow) * K + scg;
    const ushort* Bg1 = B + (size_t)(n0 + 16 * si1 + srow) * K + scg;

    gld_lds16(Ag0, &As[0][si0 * 512]);
    gld_lds16(Ag1, &As[0][si1 * 512]);
    gld_lds16(Bg0, &Bs[0][si0 * 512]);
    gld_lds16(Bg1, &Bs[0][si1 * 512]);

    const int rsw = (quad ^ (lr & 3)) * 8;
    for (int k0 = 0; k0 < K; k0 += 32) {
        const int b = (k0 >> 5) & 1;
        __syncthreads();
        if (k0 + 32 < K) {
            gld_lds16(Ag0 + k0 + 32, &As[b ^ 1][si0 * 512]);
            gld_lds16(Ag1 + k0 + 32, &As[b ^ 1][si1 * 512]);
            gld_lds16(Bg0 + k0 + 32, &Bs[b ^ 1][si0 * 512]);
            gld_lds16(Bg1 + k0 + 32, &Bs[b ^ 1][si1 * 512]);
        }
        short8 af[4], bf[4];
#pragma unroll
        for (int i = 0; i < 4; ++i) af[i] = *(const short8*)&As[b][(wm + i * 16 + lr) * 32 + rsw];
#pragma unroll
        for (int j = 0; j < 4; ++j) bf[j] = *(const short8*)&Bs[b][(wn + j * 16 + lr) * 32 + rsw];
#pragma unroll
        for (int i = 0; i < 4; ++i)
#pragma unroll
            for (int j = 0; j < 4; ++j)
                acc[i][j] = MFMA16(af[i], bf[j], acc[i][j]);
    }

    const int mbase = m0 + wm + quad * 4;
    const int nbase = n0 + wn + lr;
#pragma unroll
    for (int i = 0; i < 4; ++i)
#pragma unroll
        for (int j = 0; j < 4; ++j)
#pragma unroll
            for (int r = 0; r < 4; ++r)
                C[(size_t)(mbase + i * 16 + r) * N + (nbase + j * 16)] = acc[i][j][r];
}

// ---------------------------------------------------------------------------
// Flash attention, 128 q-rows/block, 4 waves x 32 q-rows. S^T = K@Q^T keeps
// Q in registers; K/V LDS XOR-swizzled + double-buffered, 1 barrier/tile.
// P round-trips per-wave LDS (stride 72: conflict-free). LPT: qt = 15-bx.
// ---------------------------------------------------------------------------
__global__ __launch_bounds__(256) void attn_mfma(const ushort* __restrict__ Q,
                                                 const ushort* __restrict__ K,
                                                 const ushort* __restrict__ Vt,
                                                 ushort* __restrict__ ctx, int T) {
    __shared__ __align__(16) ushort Ks[2][4096];   // [key][dim] swizzled
    __shared__ __align__(16) ushort Vs[2][4096];   // [dim][key] swizzled
    __shared__ __align__(16) ushort Ps[4][2304];   // per-wave [qrow 32][key 64] stride 72
    const int tid = threadIdx.x, w = tid >> 6, l = tid & 63;
    const int lr = l & 15, quad = l >> 4;
    const int qt = 15 - blockIdx.x;                // LPT: heavy tiles dispatch first
    const int h = blockIdx.y, hk = h >> 2;
    const int qbase = qt * 128;
    const ushort* Kb = K + (size_t)hk * T * 64;
    const ushort* Vb = Vt + (size_t)hk * 64 * T;

    // Q B-fragments in registers for the whole kernel
    short8 qf[2][2];
#pragma unroll
    for (int ni = 0; ni < 2; ++ni)
#pragma unroll
        for (int ks = 0; ks < 2; ++ks)
            qf[ni][ks] = *(const short8*)(Q + ((size_t)h * T + qbase + w * 32 + ni * 16 + lr) * 64 + ks * 32 + quad * 8);

    f32x4 zero = {0.f, 0.f, 0.f, 0.f};
    f32x4 oacc[2][4];
#pragma unroll
    for (int ni = 0; ni < 2; ++ni)
#pragma unroll
        for (int dj = 0; dj < 4; ++dj) oacc[ni][dj] = zero;
    float lsum[2] = {0.f, 0.f};

    // staging: 8 rows x 128B per DMA; swizzle c = (l&7) ^ ((l>>3)&7)
    const int srow = l >> 3;                    // 0..7
    const int sc   = ((l & 7) ^ srow) * 8;      // global chunk offset (ushorts)
    const int si0 = 2 * w, si1 = 2 * w + 1;

    const int ntiles = 2 * qt + 2;
    const int diag = 2 * qt + (w >> 1);         // per-wave diagonal tile
    const int qrow0 = qbase + w * 32 + lr;      // + 16*ni

    // prologue: stage tile 0 into buf 0
    gld_lds16(Kb + (size_t)(8 * si0 + srow) * 64 + sc, &Ks[0][si0 * 512]);
    gld_lds16(Kb + (size_t)(8 * si1 + srow) * 64 + sc, &Ks[0][si1 * 512]);
    gld_lds16(Vb + (size_t)(8 * si0 + srow) * T + sc, &Vs[0][si0 * 512]);
    gld_lds16(Vb + (size_t)(8 * si1 + srow) * T + sc, &Vs[0][si1 * 512]);

    const int swz = (lr & 7);
    for (int kt = 0; kt < ntiles; ++kt) {
        const int b = kt & 1;
        __syncthreads();
        if (kt + 1 < ntiles) {
            const int k0n = (kt + 1) * 64;
            gld_lds16(Kb + (size_t)(k0n + 8 * si0 + srow) * 64 + sc, &Ks[b ^ 1][si0 * 512]);
            gld_lds16(Kb + (size_t)(k0n + 8 * si1 + srow) * 64 + sc, &Ks[b ^ 1][si1 * 512]);
            gld_lds16(Vb + (size_t)(8 * si0 + srow) * T + k0n + sc, &Vs[b ^ 1][si0 * 512]);
            gld_lds16(Vb + (size_t)(8 * si1 + srow) * T + k0n + sc, &Vs[b ^ 1][si1 * 512]);
        }
        if (kt > diag) continue;   // wave has no work, but staged + hit barrier
        const int k0 = kt * 64;

        // S^T = K @ Q^T : D[m=key][n=qrow]
        f32x4 s[4][2];
#pragma unroll
        for (int mi = 0; mi < 4; ++mi)
#pragma unroll
            for (int ni = 0; ni < 2; ++ni) s[mi][ni] = zero;
#pragma unroll
        for (int ks = 0; ks < 2; ++ks)
#pragma unroll
            for (int mi = 0; mi < 4; ++mi) {
                short8 kf = *(const short8*)&Ks[b][(mi * 16 + lr) * 64 + ((4 * ks + quad) ^ swz) * 8];
                s[mi][0] = MFMA16(kf, qf[0][ks], s[mi][0]);
                s[mi][1] = MFMA16(kf, qf[1][ks], s[mi][1]);
            }

        // exp (+ mask on diagonal tile) -> Ps as ushort4 (4 consecutive keys)
        const bool masked = (kt == diag);
#pragma unroll
        for (int mi = 0; mi < 4; ++mi)
#pragma unroll
            for (int ni = 0; ni < 2; ++ni) {
                float pv[4];
#pragma unroll
                for (int r = 0; r < 4; ++r) {
                    float p = __expf(s[mi][ni][r] * 0.125f);
                    if (masked && (k0 + mi * 16 + quad * 4 + r > qrow0 + ni * 16)) p = 0.f;
                    lsum[ni] += p;
                    pv[r] = p;
                }
                ushort4 pk;
                pk.x = f2bf(pv[0]); pk.y = f2bf(pv[1]); pk.z = f2bf(pv[2]); pk.w = f2bf(pv[3]);
                *(ushort4*)&Ps[w][(ni * 16 + lr) * 72 + mi * 16 + quad * 4] = pk;
            }

        // O += P @ V^T : A=P[qrow][key] from Ps, B=V[dim][key] from Vs
#pragma unroll
        for (int ks2 = 0; ks2 < 2; ++ks2) {
            short8 pf0 = *(const short8*)&Ps[w][lr * 72 + ks2 * 32 + quad * 8];
            short8 pf1 = *(const short8*)&Ps[w][(16 + lr) * 72 + ks2 * 32 + quad * 8];
#pragma unroll
            for (int dj = 0; dj < 4; ++dj) {
                short8 vf = *(const short8*)&Vs[b][(dj * 16 + lr) * 64 + ((4 * ks2 + quad) ^ swz) * 8];
                oacc[0][dj] = MFMA16(pf0, vf, oacc[0][dj]);
                oacc[1][dj] = MFMA16(pf1, vf, oacc[1][dj]);
            }
        }
    }

    // softmax denominators: reduce over quads, then redistribute to C-layout rows
    float inv[2][4];
#pragma unroll
    for (int ni = 0; ni < 2; ++ni) {
        float v = lsum[ni];
        v += __shfl_xor(v, 16, 64);
        v += __shfl_xor(v, 32, 64);
#pragma unroll
        for (int r = 0; r < 4; ++r)
            inv[ni][r] = 1.f / __shfl(v, quad * 4 + r, 64);
    }

    // write ctx [t][2048] bf16
#pragma unroll
    for (int ni = 0; ni < 2; ++ni)
#pragma unroll
        for (int dj = 0; dj < 4; ++dj) {
            int col = h * 64 + dj * 16 + lr;
#pragma unroll
            for (int r = 0; r < 4; ++r) {
                int row = qbase + w * 32 + ni * 16 + quad * 4 + r;
                ctx[(size_t)row * 2048 + col] = f2bf(oacc[ni][dj][r] * inv[ni][r]);
            }
        }
}

// ---------------------------------------------------------------------------
extern "C" void kernel_launch(void* const* d_in, const int* in_sizes, int n_in,
                              void* d_out, int out_size, void* d_ws, size_t ws_size,
                              hipStream_t stream) {
    const float* x  = (const float*)d_in[0];
    const float* Wq = (const float*)d_in[1];
    const float* Wk = (const float*)d_in[2];
    const float* Wv = (const float*)d_in[3];
    const float* Wo = (const float*)d_in[4];
    const int* start_pos = (const int*)d_in[5];
    float* out = (float*)d_out;

    const int T = T_SEQ, D = D_MODEL;
    const int KV = N_KV * HEAD_DIM;  // 512

    char* w = (char*)d_ws;
    float* cosT = (float*)w;            w += (size_t)32 * T * 4;
    float* sinT = (float*)w;            w += (size_t)32 * T * 4;
    ushort* xbf  = (ushort*)w;          w += (size_t)T * D * 2;     // aliased: ctx
    ushort* wqbf = (ushort*)w;          w += (size_t)D * D * 2;
    ushort* wkbf = (ushort*)w;          w += (size_t)KV * D * 2;
    ushort* wvbf = (ushort*)w;          w += (size_t)KV * D * 2;
    ushort* wobf = (ushort*)w;          w += (size_t)D * D * 2;
    ushort* qbf  = (ushort*)w;          w += (size_t)N_HEADS * T * 64 * 2;
    ushort* kbf  = (ushort*)w;          w += (size_t)N_KV * T * 64 * 2;
    ushort* vtbf = (ushort*)w;          w += (size_t)N_KV * 64 * T * 2;
    ushort* ctxbf = xbf;  // x fully consumed by gemm_qkv before attn writes ctx

    rope_tables_kernel<<<dim3(T), dim3(32), 0, stream>>>(cosT, sinT, start_pos, T);

    cast_all_kernel<<<dim3(14336), dim3(256), 0, stream>>>(x, Wq, Wk, Wv, Wo,
                                                           xbf, wqbf, wkbf, wvbf, wobf);

    gemm_qkv<<<dim3(T / 128, (D + 2 * KV) / 128), dim3(256), 0, stream>>>(
        xbf, wqbf, wkbf, wvbf, qbf, kbf, vtbf, cosT, sinT, T, D);

    attn_mfma<<<dim3(T / 128, N_HEADS), dim3(256), 0, stream>>>(qbf, kbf, vtbf, ctxbf, T);

    gemm_bt_f32<<<dim3(T / 128, D / 128), dim3(256), 0, stream>>>(ctxbf, wobf, out, T, D, D);
}

// Round 5
// 251.535 us; speedup vs baseline: 1.0770x; 1.0770x over previous
//
#include <hip/hip_runtime.h>
#include <math.h>

#define T_SEQ 2048
#define D_MODEL 2048
#define HEAD_DIM 64
#define N_HEADS 32
#define N_KV 8

using short8 = __attribute__((ext_vector_type(8))) short;
using f32x4  = __attribute__((ext_vector_type(4))) float;

#define MFMA16(a, b, c) __builtin_amdgcn_mfma_f32_16x16x32_bf16(a, b, c, 0, 0, 0)

__device__ __forceinline__ unsigned short f2bf(float f) {
    unsigned int u = __builtin_bit_cast(unsigned int, f);
    u += 0x7fff + ((u >> 16) & 1);
    return (unsigned short)(u >> 16);
}
__device__ __forceinline__ float bf2f(unsigned short h) {
    unsigned int u = ((unsigned int)h) << 16;
    return __builtin_bit_cast(float, u);
}
__device__ __forceinline__ void gld_lds16(const ushort* g, ushort* l) {
    __builtin_amdgcn_global_load_lds((const __attribute__((address_space(1))) void*)g,
                                     (__attribute__((address_space(3))) void*)l, 16, 0, 0);
}

// ---------------------------------------------------------------------------
// RoPE tables (llama3 scaling), fp32, transposed [i][T]
// ---------------------------------------------------------------------------
__global__ void rope_tables_kernel(float* __restrict__ cosT, float* __restrict__ sinT,
                                   const int* __restrict__ start_pos, int T) {
    int t = blockIdx.x;
    int i = threadIdx.x;  // 0..31
    float pos = (float)(start_pos[0] + t);
    float expo = (float)i / 32.0f;
    float inv_freq = 1.0f / powf(500000.0f, expo);
    const float two_pi = 6.283185307179586f;
    float wavelen = two_pi / inv_freq;
    const float low_wl = 8192.0f;
    const float high_wl = 2048.0f;
    float inv;
    if (wavelen > low_wl) {
        inv = inv_freq / 32.0f;
    } else if (wavelen < high_wl) {
        inv = inv_freq;
    } else {
        float smooth = (8192.0f / wavelen - 1.0f) / 3.0f;
        inv = (1.0f - smooth) * (inv_freq / 32.0f) + smooth * inv_freq;
    }
    float ang = pos * inv;
    cosT[i * T + t] = cosf(ang);
    sinT[i * T + t] = sinf(ang);
}

// ---------------------------------------------------------------------------
// One cast kernel for all five fp32->bf16 conversions (float4 granules)
// ---------------------------------------------------------------------------
__global__ __launch_bounds__(256) void cast_all_kernel(
    const float* __restrict__ x, const float* __restrict__ wq,
    const float* __restrict__ wk, const float* __restrict__ wv,
    const float* __restrict__ wo,
    ushort* __restrict__ xb, ushort* __restrict__ wqb,
    ushort* __restrict__ wkb, ushort* __restrict__ wvb, ushort* __restrict__ wob) {
    int i = blockIdx.x * 256 + threadIdx.x;
    const float* src; ushort* dst; int off;
    if (i < 1048576)      { src = x;  dst = xb;  off = i; }
    else if (i < 2097152) { src = wq; dst = wqb; off = i - 1048576; }
    else if (i < 2359296) { src = wk; dst = wkb; off = i - 2097152; }
    else if (i < 2621440) { src = wv; dst = wvb; off = i - 2359296; }
    else                  { src = wo; dst = wob; off = i - 2621440; }
    float4 v = ((const float4*)src)[off];
    ushort4 o;
    o.x = f2bf(v.x); o.y = f2bf(v.y); o.z = f2bf(v.z); o.w = f2bf(v.w);
    ((ushort4*)dst)[off] = o;
}

// ---------------------------------------------------------------------------
// Fused QKV GEMM + RoPE epilogue. 64x128 tile (M x N), BK=32, dbuf LDS,
// XOR-swizzled chunks, 1 barrier/K-step. Grid 32 x 24 = 768 blocks (3/CU).
// grid.y: 0..15 Q (rope), 16..19 K (rope), 20..23 V (transposed, no rope).
// Wave layout 2x2: wm=(w>>1)*32 rows, wn=(w&1)*64 cols; acc[2][4].
// ---------------------------------------------------------------------------
__global__ __launch_bounds__(256) void gemm_qkv(
    const ushort* __restrict__ X, const ushort* __restrict__ Wqb,
    const ushort* __restrict__ Wkb, const ushort* __restrict__ Wvb,
    ushort* __restrict__ Qo, ushort* __restrict__ Ko, ushort* __restrict__ Vto,
    const float* __restrict__ cosT, const float* __restrict__ sinT,
    int T, int D) {
    __shared__ __align__(16) ushort As[2][2048];   // 64 x 32
    __shared__ __align__(16) ushort Bs[2][4096];   // 128 x 32
    const int tid = threadIdx.x;
    const int w = tid >> 6, l = tid & 63;
    const int m0 = blockIdx.x * 64;
    const int n0g = blockIdx.y * 128;

    const ushort* B;
    ushort* Cout;
    int n0, doRope;
    if (n0g < 2048)      { B = Wqb + (size_t)n0g * D;          Cout = Qo;  n0 = n0g;        doRope = 1; }
    else if (n0g < 2560) { B = Wkb + (size_t)(n0g - 2048) * D; Cout = Ko;  n0 = n0g - 2048; doRope = 1; }
    else                 { B = Wvb + (size_t)(n0g - 2560) * D; Cout = Vto; n0 = n0g - 2560; doRope = 0; }

    const int wm = (w >> 1) * 32, wn = (w & 1) * 64;
    const int lr = l & 15;
    const int quad = l >> 4;

    f32x4 zero = {0.f, 0.f, 0.f, 0.f};
    f32x4 acc[2][4];
#pragma unroll
    for (int i = 0; i < 2; ++i)
#pragma unroll
        for (int j = 0; j < 4; ++j) acc[i][j] = zero;

    // staging: row = 32 ushorts = 4 chunks of 16B; stored chunk p, global c = p ^ (row&3)
    const int srow = l >> 2;                       // 0..15
    const int scg  = ((l & 3) ^ (srow & 3)) * 8;   // global chunk offset (ushorts)
    // wave w: A seg w (16 rows), B segs 2w, 2w+1
    const ushort* Ag0 = X + (size_t)(m0 + 16 * w + srow) * D + scg;
    const ushort* Bg0 = B + (size_t)(16 * (2 * w) + srow) * D + scg;
    const ushort* Bg1 = B + (size_t)(16 * (2 * w + 1) + srow) * D + scg;

    gld_lds16(Ag0, &As[0][w * 512]);
    gld_lds16(Bg0, &Bs[0][(2 * w) * 512]);
    gld_lds16(Bg1, &Bs[0][(2 * w + 1) * 512]);

    const int rsw = (quad ^ (lr & 3)) * 8;
    for (int k0 = 0; k0 < D; k0 += 32) {
        const int b = (k0 >> 5) & 1;
        __syncthreads();
        if (k0 + 32 < D) {
            gld_lds16(Ag0 + k0 + 32, &As[b ^ 1][w * 512]);
            gld_lds16(Bg0 + k0 + 32, &Bs[b ^ 1][(2 * w) * 512]);
            gld_lds16(Bg1 + k0 + 32, &Bs[b ^ 1][(2 * w + 1) * 512]);
        }
        short8 af[2], bf[4];
#pragma unroll
        for (int i = 0; i < 2; ++i) af[i] = *(const short8*)&As[b][(wm + i * 16 + lr) * 32 + rsw];
#pragma unroll
        for (int j = 0; j < 4; ++j) bf[j] = *(const short8*)&Bs[b][(wn + j * 16 + lr) * 32 + rsw];
#pragma unroll
        for (int i = 0; i < 2; ++i)
#pragma unroll
            for (int j = 0; j < 4; ++j)
                acc[i][j] = MFMA16(af[i], bf[j], acc[i][j]);
    }

    const int mbase = m0 + wm + quad * 4;
    if (doRope) {
        // wave's 64-col span = one head; acc[i][j] (j=0,1) dim i1=lr+j*16, acc[i][j+2] dim i1+32
#pragma unroll
        for (int i = 0; i < 2; ++i) {
            int trow = mbase + i * 16;
#pragma unroll
            for (int j = 0; j < 2; ++j) {
                int i1 = lr + j * 16;
                float4 c4 = *(const float4*)&cosT[(size_t)i1 * T + trow];
                float4 s4 = *(const float4*)&sinT[(size_t)i1 * T + trow];
                int n1 = n0 + wn + lr + j * 16;
                int n2 = n1 + 32;
                size_t b1 = (size_t)(n1 >> 6) * ((size_t)T * 64) + (size_t)(n1 & 63);
                size_t b2 = (size_t)(n2 >> 6) * ((size_t)T * 64) + (size_t)(n2 & 63);
                float cs[4] = {c4.x, c4.y, c4.z, c4.w};
                float sn[4] = {s4.x, s4.y, s4.z, s4.w};
#pragma unroll
                for (int r = 0; r < 4; ++r) {
                    float x1 = acc[i][j][r], x2 = acc[i][j + 2][r];
                    Cout[b1 + (size_t)(trow + r) * 64] = f2bf(x1 * cs[r] - x2 * sn[r]);
                    Cout[b2 + (size_t)(trow + r) * 64] = f2bf(x2 * cs[r] + x1 * sn[r]);
                }
            }
        }
    } else {
#pragma unroll
        for (int i = 0; i < 2; ++i)
#pragma unroll
            for (int j = 0; j < 4; ++j) {
                int n = n0 + wn + lr + j * 16;
                int m = mbase + i * 16;
                ushort4 o;
                o.x = f2bf(acc[i][j][0]); o.y = f2bf(acc[i][j][1]);
                o.z = f2bf(acc[i][j][2]); o.w = f2bf(acc[i][j][3]);
                *(ushort4*)&Vto[(size_t)n * T + m] = o;
            }
    }
}

// ---------------------------------------------------------------------------
// Output projection GEMM (C fp32), same 64x128 dbuf+swizzle core.
// Grid 32 x 16 = 512 blocks (2/CU uniform).
// ---------------------------------------------------------------------------
__global__ __launch_bounds__(256) void gemm_bt_f32(const ushort* __restrict__ A,
                                                   const ushort* __restrict__ B,
                                                   float* __restrict__ C,
                                                   int M, int N, int K) {
    __shared__ __align__(16) ushort As[2][2048];
    __shared__ __align__(16) ushort Bs[2][4096];
    const int tid = threadIdx.x;
    const int w = tid >> 6, l = tid & 63;
    const int m0 = blockIdx.x * 64, n0 = blockIdx.y * 128;
    const int wm = (w >> 1) * 32, wn = (w & 1) * 64;
    const int lr = l & 15;
    const int quad = l >> 4;

    f32x4 zero = {0.f, 0.f, 0.f, 0.f};
    f32x4 acc[2][4];
#pragma unroll
    for (int i = 0; i < 2; ++i)
#pragma unroll
        for (int j = 0; j < 4; ++j) acc[i][j] = zero;

    const int srow = l >> 2;
    const int scg  = ((l & 3) ^ (srow & 3)) * 8;
    const ushort* Ag0 = A + (size_t)(m0 + 16 * w + srow) * K + scg;
    const ushort* Bg0 = B + (size_t)(n0 + 16 * (2 * w) + srow) * K + scg;
    const ushort* Bg1 = B + (size_t)(n0 + 16 * (2 * w + 1) + srow) * K + scg;

    gld_lds16(Ag0, &As[0][w * 512]);
    gld_lds16(Bg0, &Bs[0][(2 * w) * 512]);
    gld_lds16(Bg1, &Bs[0][(2 * w + 1) * 512]);

    const int rsw = (quad ^ (lr & 3)) * 8;
    for (int k0 = 0; k0 < K; k0 += 32) {
        const int b = (k0 >> 5) & 1;
        __syncthreads();
        if (k0 + 32 < K) {
            gld_lds16(Ag0 + k0 + 32, &As[b ^ 1][w * 512]);
            gld_lds16(Bg0 + k0 + 32, &Bs[b ^ 1][(2 * w) * 512]);
            gld_lds16(Bg1 + k0 + 32, &Bs[b ^ 1][(2 * w + 1) * 512]);
        }
        short8 af[2], bf[4];
#pragma unroll
        for (int i = 0; i < 2; ++i) af[i] = *(const short8*)&As[b][(wm + i * 16 + lr) * 32 + rsw];
#pragma unroll
        for (int j = 0; j < 4; ++j) bf[j] = *(const short8*)&Bs[b][(wn + j * 16 + lr) * 32 + rsw];
#pragma unroll
        for (int i = 0; i < 2; ++i)
#pragma unroll
            for (int j = 0; j < 4; ++j)
                acc[i][j] = MFMA16(af[i], bf[j], acc[i][j]);
    }

    const int mbase = m0 + wm + quad * 4;
    const int nbase = n0 + wn + lr;
#pragma unroll
    for (int i = 0; i < 2; ++i)
#pragma unroll
        for (int j = 0; j < 4; ++j)
#pragma unroll
            for (int r = 0; r < 4; ++r)
                C[(size_t)(mbase + i * 16 + r) * N + (nbase + j * 16)] = acc[i][j][r];
}

// ---------------------------------------------------------------------------
// Flash attention: grid (8, 32); block runs TWO q-tiles (15-bx then bx) of
// 128 rows -> exactly 34 k-tiles per block, 256 uniform blocks. 4 waves x
// 32 q-rows, S^T = K@Q^T (Q in regs), XOR-swizzled dbuf K/V LDS, 1 barrier
// per tile. P via per-wave LDS stride 72 (conflict-free).
// ---------------------------------------------------------------------------
__global__ __launch_bounds__(256) void attn_mfma(const ushort* __restrict__ Q,
                                                 const ushort* __restrict__ K,
                                                 const ushort* __restrict__ Vt,
                                                 ushort* __restrict__ ctx, int T) {
    __shared__ __align__(16) ushort Ks[2][4096];   // [key][dim] swizzled
    __shared__ __align__(16) ushort Vs[2][4096];   // [dim][key] swizzled
    __shared__ __align__(16) ushort Ps[4][2304];   // per-wave [qrow 32][key 64] stride 72
    const int tid = threadIdx.x, w = tid >> 6, l = tid & 63;
    const int lr = l & 15, quad = l >> 4;
    const int h = blockIdx.y, hk = h >> 2;
    const ushort* Kb = K + (size_t)hk * T * 64;
    const ushort* Vb = Vt + (size_t)hk * 64 * T;

    const int srow = l >> 3;                    // 0..7
    const int sc   = ((l & 7) ^ srow) * 8;      // global chunk offset (ushorts)
    const int si0 = 2 * w, si1 = 2 * w + 1;
    const int swz = (lr & 7);
    f32x4 zero = {0.f, 0.f, 0.f, 0.f};

    for (int phase = 0; phase < 2; ++phase) {
        const int qt = phase == 0 ? (15 - (int)blockIdx.x) : (int)blockIdx.x;
        const int qbase = qt * 128;

        // Q B-fragments in registers for this phase
        short8 qf[2][2];
#pragma unroll
        for (int ni = 0; ni < 2; ++ni)
#pragma unroll
            for (int ks = 0; ks < 2; ++ks)
                qf[ni][ks] = *(const short8*)(Q + ((size_t)h * T + qbase + w * 32 + ni * 16 + lr) * 64 + ks * 32 + quad * 8);

        f32x4 oacc[2][4];
#pragma unroll
        for (int ni = 0; ni < 2; ++ni)
#pragma unroll
            for (int dj = 0; dj < 4; ++dj) oacc[ni][dj] = zero;
        float lsum[2] = {0.f, 0.f};

        const int ntiles = 2 * qt + 2;          // even -> last buffer is 1, prologue uses 0
        const int diag = 2 * qt + (w >> 1);
        const int qrow0 = qbase + w * 32 + lr;

        gld_lds16(Kb + (size_t)(8 * si0 + srow) * 64 + sc, &Ks[0][si0 * 512]);
        gld_lds16(Kb + (size_t)(8 * si1 + srow) * 64 + sc, &Ks[0][si1 * 512]);
        gld_lds16(Vb + (size_t)(8 * si0 + srow) * T + sc, &Vs[0][si0 * 512]);
        gld_lds16(Vb + (size_t)(8 * si1 + srow) * T + sc, &Vs[0][si1 * 512]);

        for (int kt = 0; kt < ntiles; ++kt) {
            const int b = kt & 1;
            __syncthreads();
            if (kt + 1 < ntiles) {
                const int k0n = (kt + 1) * 64;
                gld_lds16(Kb + (size_t)(k0n + 8 * si0 + srow) * 64 + sc, &Ks[b ^ 1][si0 * 512]);
                gld_lds16(Kb + (size_t)(k0n + 8 * si1 + srow) * 64 + sc, &Ks[b ^ 1][si1 * 512]);
                gld_lds16(Vb + (size_t)(8 * si0 + srow) * T + k0n + sc, &Vs[b ^ 1][si0 * 512]);
                gld_lds16(Vb + (size_t)(8 * si1 + srow) * T + k0n + sc, &Vs[b ^ 1][si1 * 512]);
            }
            if (kt > diag) continue;   // staged + barrier, no compute
            const int k0 = kt * 64;

            // S^T = K @ Q^T : D[m=key][n=qrow]
            f32x4 s[4][2];
#pragma unroll
            for (int mi = 0; mi < 4; ++mi)
#pragma unroll
                for (int ni = 0; ni < 2; ++ni) s[mi][ni] = zero;
#pragma unroll
            for (int ks = 0; ks < 2; ++ks)
#pragma unroll
                for (int mi = 0; mi < 4; ++mi) {
                    short8 kf = *(const short8*)&Ks[b][(mi * 16 + lr) * 64 + ((4 * ks + quad) ^ swz) * 8];
                    s[mi][0] = MFMA16(kf, qf[0][ks], s[mi][0]);
                    s[mi][1] = MFMA16(kf, qf[1][ks], s[mi][1]);
                }

            // exp (+ mask on diagonal tile) -> Ps as ushort4 (4 consecutive keys)
            const bool masked = (kt == diag);
#pragma unroll
            for (int mi = 0; mi < 4; ++mi)
#pragma unroll
                for (int ni = 0; ni < 2; ++ni) {
                    float pv[4];
#pragma unroll
                    for (int r = 0; r < 4; ++r) {
                        float p = __expf(s[mi][ni][r] * 0.125f);
                        if (masked && (k0 + mi * 16 + quad * 4 + r > qrow0 + ni * 16)) p = 0.f;
                        lsum[ni] += p;
                        pv[r] = p;
                    }
                    ushort4 pk;
                    pk.x = f2bf(pv[0]); pk.y = f2bf(pv[1]); pk.z = f2bf(pv[2]); pk.w = f2bf(pv[3]);
                    *(ushort4*)&Ps[w][(ni * 16 + lr) * 72 + mi * 16 + quad * 4] = pk;
                }

            // O += P @ V^T
#pragma unroll
            for (int ks2 = 0; ks2 < 2; ++ks2) {
                short8 pf0 = *(const short8*)&Ps[w][lr * 72 + ks2 * 32 + quad * 8];
                short8 pf1 = *(const short8*)&Ps[w][(16 + lr) * 72 + ks2 * 32 + quad * 8];
#pragma unroll
                for (int dj = 0; dj < 4; ++dj) {
                    short8 vf = *(const short8*)&Vs[b][(dj * 16 + lr) * 64 + ((4 * ks2 + quad) ^ swz) * 8];
                    oacc[0][dj] = MFMA16(pf0, vf, oacc[0][dj]);
                    oacc[1][dj] = MFMA16(pf1, vf, oacc[1][dj]);
                }
            }
        }

        // softmax denominators: reduce over quads, redistribute to C-layout rows
        float inv[2][4];
#pragma unroll
        for (int ni = 0; ni < 2; ++ni) {
            float v = lsum[ni];
            v += __shfl_xor(v, 16, 64);
            v += __shfl_xor(v, 32, 64);
#pragma unroll
            for (int r = 0; r < 4; ++r)
                inv[ni][r] = 1.f / __shfl(v, quad * 4 + r, 64);
        }

        // write ctx [t][2048] bf16
#pragma unroll
        for (int ni = 0; ni < 2; ++ni)
#pragma unroll
            for (int dj = 0; dj < 4; ++dj) {
                int col = h * 64 + dj * 16 + lr;
#pragma unroll
                for (int r = 0; r < 4; ++r) {
                    int row = qbase + w * 32 + ni * 16 + quad * 4 + r;
                    ctx[(size_t)row * 2048 + col] = f2bf(oacc[ni][dj][r] * inv[ni][r]);
                }
            }
    }
}

// ---------------------------------------------------------------------------
extern "C" void kernel_launch(void* const* d_in, const int* in_sizes, int n_in,
                              void* d_out, int out_size, void* d_ws, size_t ws_size,
                              hipStream_t stream) {
    const float* x  = (const float*)d_in[0];
    const float* Wq = (const float*)d_in[1];
    const float* Wk = (const float*)d_in[2];
    const float* Wv = (const float*)d_in[3];
    const float* Wo = (const float*)d_in[4];
    const int* start_pos = (const int*)d_in[5];
    float* out = (float*)d_out;

    const int T = T_SEQ, D = D_MODEL;
    const int KV = N_KV * HEAD_DIM;  // 512

    char* w = (char*)d_ws;
    float* cosT = (float*)w;            w += (size_t)32 * T * 4;
    float* sinT = (float*)w;            w += (size_t)32 * T * 4;
    ushort* xbf  = (ushort*)w;          w += (size_t)T * D * 2;     // aliased: ctx
    ushort* wqbf = (ushort*)w;          w += (size_t)D * D * 2;
    ushort* wkbf = (ushort*)w;          w += (size_t)KV * D * 2;
    ushort* wvbf = (ushort*)w;          w += (size_t)KV * D * 2;
    ushort* wobf = (ushort*)w;          w += (size_t)D * D * 2;
    ushort* qbf  = (ushort*)w;          w += (size_t)N_HEADS * T * 64 * 2;
    ushort* kbf  = (ushort*)w;          w += (size_t)N_KV * T * 64 * 2;
    ushort* vtbf = (ushort*)w;          w += (size_t)N_KV * 64 * T * 2;
    ushort* ctxbf = xbf;  // x fully consumed by gemm_qkv before attn writes ctx

    rope_tables_kernel<<<dim3(T), dim3(32), 0, stream>>>(cosT, sinT, start_pos, T);

    cast_all_kernel<<<dim3(14336), dim3(256), 0, stream>>>(x, Wq, Wk, Wv, Wo,
                                                           xbf, wqbf, wkbf, wvbf, wobf);

    gemm_qkv<<<dim3(T / 64, (D + 2 * KV) / 128), dim3(256), 0, stream>>>(
        xbf, wqbf, wkbf, wvbf, qbf, kbf, vtbf, cosT, sinT, T, D);

    attn_mfma<<<dim3(8, N_HEADS), dim3(256), 0, stream>>>(qbf, kbf, vtbf, ctxbf, T);

    gemm_bt_f32<<<dim3(T / 64, D / 128), dim3(256), 0, stream>>>(ctxbf, wobf, out, T, D, D);
}

// Round 6
// 218.635 us; speedup vs baseline: 1.2390x; 1.1505x over previous
//
#include <hip/hip_runtime.h>
#include <math.h>

#define T_SEQ 2048
#define D_MODEL 2048
#define HEAD_DIM 64
#define N_HEADS 32
#define N_KV 8

using short8 = __attribute__((ext_vector_type(8))) short;
using f32x4  = __attribute__((ext_vector_type(4))) float;

#define MFMA16(a, b, c) __builtin_amdgcn_mfma_f32_16x16x32_bf16(a, b, c, 0, 0, 0)

__device__ __forceinline__ unsigned short f2bf(float f) {
    unsigned int u = __builtin_bit_cast(unsigned int, f);
    u += 0x7fff + ((u >> 16) & 1);
    return (unsigned short)(u >> 16);
}
__device__ __forceinline__ void gld_lds16(const ushort* g, ushort* l) {
    __builtin_amdgcn_global_load_lds((const __attribute__((address_space(1))) void*)g,
                                     (__attribute__((address_space(3))) void*)l, 16, 0, 0);
}

// ---------------------------------------------------------------------------
// RoPE tables (llama3 scaling), fp32, transposed [i][T]
// ---------------------------------------------------------------------------
__global__ void rope_tables_kernel(float* __restrict__ cosT, float* __restrict__ sinT,
                                   const int* __restrict__ start_pos, int T) {
    int t = blockIdx.x;
    int i = threadIdx.x;  // 0..31
    float pos = (float)(start_pos[0] + t);
    float expo = (float)i / 32.0f;
    float inv_freq = 1.0f / powf(500000.0f, expo);
    const float two_pi = 6.283185307179586f;
    float wavelen = two_pi / inv_freq;
    const float low_wl = 8192.0f;
    const float high_wl = 2048.0f;
    float inv;
    if (wavelen > low_wl) {
        inv = inv_freq / 32.0f;
    } else if (wavelen < high_wl) {
        inv = inv_freq;
    } else {
        float smooth = (8192.0f / wavelen - 1.0f) / 3.0f;
        inv = (1.0f - smooth) * (inv_freq / 32.0f) + smooth * inv_freq;
    }
    float ang = pos * inv;
    cosT[i * T + t] = cosf(ang);
    sinT[i * T + t] = sinf(ang);
}

// ---------------------------------------------------------------------------
// One cast kernel for all five fp32->bf16 conversions (float4 granules)
// ---------------------------------------------------------------------------
__global__ __launch_bounds__(256) void cast_all_kernel(
    const float* __restrict__ x, const float* __restrict__ wq,
    const float* __restrict__ wk, const float* __restrict__ wv,
    const float* __restrict__ wo,
    ushort* __restrict__ xb, ushort* __restrict__ wqb,
    ushort* __restrict__ wkb, ushort* __restrict__ wvb, ushort* __restrict__ wob) {
    int i = blockIdx.x * 256 + threadIdx.x;
    const float* src; ushort* dst; int off;
    if (i < 1048576)      { src = x;  dst = xb;  off = i; }
    else if (i < 2097152) { src = wq; dst = wqb; off = i - 1048576; }
    else if (i < 2359296) { src = wk; dst = wkb; off = i - 2097152; }
    else if (i < 2621440) { src = wv; dst = wvb; off = i - 2359296; }
    else                  { src = wo; dst = wob; off = i - 2621440; }
    float4 v = ((const float4*)src)[off];
    ushort4 o;
    o.x = f2bf(v.x); o.y = f2bf(v.y); o.z = f2bf(v.z); o.w = f2bf(v.w);
    ((ushort4*)dst)[off] = o;
}

// ---------------------------------------------------------------------------
// Fused QKV GEMM + RoPE epilogue. 64x128 tile, BK=64 as 2x BK=32 sub-tiles
// per barrier (half the barrier count of R5), dbuf, XOR-swizzled. Grid
// 32 x 24 = 768 blocks (3/CU). grid.y: 0..15 Q, 16..19 K, 20..23 V(transposed)
// ---------------------------------------------------------------------------
__global__ __launch_bounds__(256) void gemm_qkv(
    const ushort* __restrict__ X, const ushort* __restrict__ Wqb,
    const ushort* __restrict__ Wkb, const ushort* __restrict__ Wvb,
    ushort* __restrict__ Qo, ushort* __restrict__ Ko, ushort* __restrict__ Vto,
    const float* __restrict__ cosT, const float* __restrict__ sinT,
    int T, int D) {
    __shared__ __align__(16) ushort As[2][2][2048];   // [buf][sub][64x32]
    __shared__ __align__(16) ushort Bs[2][2][4096];   // [buf][sub][128x32]
    const int tid = threadIdx.x;
    const int w = tid >> 6, l = tid & 63;
    const int m0 = blockIdx.x * 64;
    const int n0g = blockIdx.y * 128;

    const ushort* B;
    ushort* Cout;
    int n0, doRope;
    if (n0g < 2048)      { B = Wqb + (size_t)n0g * D;          Cout = Qo;  n0 = n0g;        doRope = 1; }
    else if (n0g < 2560) { B = Wkb + (size_t)(n0g - 2048) * D; Cout = Ko;  n0 = n0g - 2048; doRope = 1; }
    else                 { B = Wvb + (size_t)(n0g - 2560) * D; Cout = Vto; n0 = n0g - 2560; doRope = 0; }

    const int wm = (w >> 1) * 32, wn = (w & 1) * 64;
    const int lr = l & 15;
    const int quad = l >> 4;

    f32x4 zero = {0.f, 0.f, 0.f, 0.f};
    f32x4 acc[2][4];
#pragma unroll
    for (int i = 0; i < 2; ++i)
#pragma unroll
        for (int j = 0; j < 4; ++j) acc[i][j] = zero;

    const int srow = l >> 2;                       // 0..15
    const int scg  = ((l & 3) ^ (srow & 3)) * 8;   // swizzled global chunk
    const ushort* Ag  = X + (size_t)(m0 + 16 * w + srow) * D + scg;
    const ushort* Bg0 = B + (size_t)(16 * (2 * w) + srow) * D + scg;
    const ushort* Bg1 = B + (size_t)(16 * (2 * w + 1) + srow) * D + scg;

#define GSTAGE(k0v, nb) { \
    gld_lds16(Ag  + (k0v),      &As[nb][0][w * 512]); \
    gld_lds16(Ag  + (k0v) + 32, &As[nb][1][w * 512]); \
    gld_lds16(Bg0 + (k0v),      &Bs[nb][0][(2 * w) * 512]); \
    gld_lds16(Bg0 + (k0v) + 32, &Bs[nb][1][(2 * w) * 512]); \
    gld_lds16(Bg1 + (k0v),      &Bs[nb][0][(2 * w + 1) * 512]); \
    gld_lds16(Bg1 + (k0v) + 32, &Bs[nb][1][(2 * w + 1) * 512]); }

    GSTAGE(0, 0);

    const int rsw = (quad ^ (lr & 3)) * 8;
    for (int k0 = 0; k0 < D; k0 += 64) {
        const int b = (k0 >> 6) & 1;
        __syncthreads();
        if (k0 + 64 < D) GSTAGE(k0 + 64, b ^ 1);
#pragma unroll
        for (int sub = 0; sub < 2; ++sub) {
            short8 af[2], bf[4];
#pragma unroll
            for (int i = 0; i < 2; ++i) af[i] = *(const short8*)&As[b][sub][(wm + i * 16 + lr) * 32 + rsw];
#pragma unroll
            for (int j = 0; j < 4; ++j) bf[j] = *(const short8*)&Bs[b][sub][(wn + j * 16 + lr) * 32 + rsw];
#pragma unroll
            for (int i = 0; i < 2; ++i)
#pragma unroll
                for (int j = 0; j < 4; ++j)
                    acc[i][j] = MFMA16(af[i], bf[j], acc[i][j]);
        }
    }
#undef GSTAGE

    const int mbase = m0 + wm + quad * 4;
    if (doRope) {
#pragma unroll
        for (int i = 0; i < 2; ++i) {
            int trow = mbase + i * 16;
#pragma unroll
            for (int j = 0; j < 2; ++j) {
                int i1 = lr + j * 16;
                float4 c4 = *(const float4*)&cosT[(size_t)i1 * T + trow];
                float4 s4 = *(const float4*)&sinT[(size_t)i1 * T + trow];
                int n1 = n0 + wn + lr + j * 16;
                int n2 = n1 + 32;
                size_t b1 = (size_t)(n1 >> 6) * ((size_t)T * 64) + (size_t)(n1 & 63);
                size_t b2 = (size_t)(n2 >> 6) * ((size_t)T * 64) + (size_t)(n2 & 63);
                float cs[4] = {c4.x, c4.y, c4.z, c4.w};
                float sn[4] = {s4.x, s4.y, s4.z, s4.w};
#pragma unroll
                for (int r = 0; r < 4; ++r) {
                    float x1 = acc[i][j][r], x2 = acc[i][j + 2][r];
                    Cout[b1 + (size_t)(trow + r) * 64] = f2bf(x1 * cs[r] - x2 * sn[r]);
                    Cout[b2 + (size_t)(trow + r) * 64] = f2bf(x2 * cs[r] + x1 * sn[r]);
                }
            }
        }
    } else {
#pragma unroll
        for (int i = 0; i < 2; ++i)
#pragma unroll
            for (int j = 0; j < 4; ++j) {
                int n = n0 + wn + lr + j * 16;
                int m = mbase + i * 16;
                ushort4 o;
                o.x = f2bf(acc[i][j][0]); o.y = f2bf(acc[i][j][1]);
                o.z = f2bf(acc[i][j][2]); o.w = f2bf(acc[i][j][3]);
                *(ushort4*)&Vto[(size_t)n * T + m] = o;
            }
    }
}

// ---------------------------------------------------------------------------
// Output projection GEMM (C fp32), same BK=64 dual-sub-tile core
// ---------------------------------------------------------------------------
__global__ __launch_bounds__(256) void gemm_bt_f32(const ushort* __restrict__ A,
                                                   const ushort* __restrict__ B,
                                                   float* __restrict__ C,
                                                   int M, int N, int K) {
    __shared__ __align__(16) ushort As[2][2][2048];
    __shared__ __align__(16) ushort Bs[2][2][4096];
    const int tid = threadIdx.x;
    const int w = tid >> 6, l = tid & 63;
    const int m0 = blockIdx.x * 64, n0 = blockIdx.y * 128;
    const int wm = (w >> 1) * 32, wn = (w & 1) * 64;
    const int lr = l & 15;
    const int quad = l >> 4;

    f32x4 zero = {0.f, 0.f, 0.f, 0.f};
    f32x4 acc[2][4];
#pragma unroll
    for (int i = 0; i < 2; ++i)
#pragma unroll
        for (int j = 0; j < 4; ++j) acc[i][j] = zero;

    const int srow = l >> 2;
    const int scg  = ((l & 3) ^ (srow & 3)) * 8;
    const ushort* Ag  = A + (size_t)(m0 + 16 * w + srow) * K + scg;
    const ushort* Bg0 = B + (size_t)(n0 + 16 * (2 * w) + srow) * K + scg;
    const ushort* Bg1 = B + (size_t)(n0 + 16 * (2 * w + 1) + srow) * K + scg;

#define GSTAGE(k0v, nb) { \
    gld_lds16(Ag  + (k0v),      &As[nb][0][w * 512]); \
    gld_lds16(Ag  + (k0v) + 32, &As[nb][1][w * 512]); \
    gld_lds16(Bg0 + (k0v),      &Bs[nb][0][(2 * w) * 512]); \
    gld_lds16(Bg0 + (k0v) + 32, &Bs[nb][1][(2 * w) * 512]); \
    gld_lds16(Bg1 + (k0v),      &Bs[nb][0][(2 * w + 1) * 512]); \
    gld_lds16(Bg1 + (k0v) + 32, &Bs[nb][1][(2 * w + 1) * 512]); }

    GSTAGE(0, 0);

    const int rsw = (quad ^ (lr & 3)) * 8;
    for (int k0 = 0; k0 < K; k0 += 64) {
        const int b = (k0 >> 6) & 1;
        __syncthreads();
        if (k0 + 64 < K) GSTAGE(k0 + 64, b ^ 1);
#pragma unroll
        for (int sub = 0; sub < 2; ++sub) {
            short8 af[2], bf[4];
#pragma unroll
            for (int i = 0; i < 2; ++i) af[i] = *(const short8*)&As[b][sub][(wm + i * 16 + lr) * 32 + rsw];
#pragma unroll
            for (int j = 0; j < 4; ++j) bf[j] = *(const short8*)&Bs[b][sub][(wn + j * 16 + lr) * 32 + rsw];
#pragma unroll
            for (int i = 0; i < 2; ++i)
#pragma unroll
                for (int j = 0; j < 4; ++j)
                    acc[i][j] = MFMA16(af[i], bf[j], acc[i][j]);
        }
    }
#undef GSTAGE

    const int mbase = m0 + wm + quad * 4;
    const int nbase = n0 + wn + lr;
#pragma unroll
    for (int i = 0; i < 2; ++i)
#pragma unroll
        for (int j = 0; j < 4; ++j)
#pragma unroll
            for (int r = 0; r < 4; ++r)
                C[(size_t)(mbase + i * 16 + r) * N + (nbase + j * 16)] = acc[i][j][r];
}

// ---------------------------------------------------------------------------
// Flash attention, 512 threads = 8 waves: waves 0-3 = row-groups x EVEN
// k-tiles, waves 4-7 = same rows x ODD k-tiles (key-parity split; linear
// softmax merge since no max-shift). Grid (8,32) = 256 blocks, phase-paired
// q-tiles (15-bx, bx) -> deterministic balance AND 8 waves/CU = 2/SIMD.
// K/V: dbuf x parity, XOR-swizzled, 1 barrier per 128-key super-step.
// ---------------------------------------------------------------------------
__global__ __launch_bounds__(512) void attn_mfma(const ushort* __restrict__ Q,
                                                 const ushort* __restrict__ K,
                                                 const ushort* __restrict__ Vt,
                                                 ushort* __restrict__ ctx, int T) {
    __shared__ __align__(16) ushort Ks[2][2][4096];   // [buf][parity][key64 x dim64]
    __shared__ __align__(16) ushort Vs[2][2][4096];   // [buf][parity][dim64 x key64]
    __shared__ __align__(16) ushort Ps[8][2304];      // per-wave [qrow32][key64] stride 72
    float* mrg = (float*)&Ps[0][0];                   // merge view (Ps dead at merge time)

    const int tid = threadIdx.x, w = tid >> 6, l = tid & 63;
    const int pw = w >> 2;          // key parity of this wave
    const int rg = w & 3;           // q-row group (32 rows each)
    const int lr = l & 15, quad = l >> 4;
    const int h = blockIdx.y, hk = h >> 2;
    const ushort* Kb = K + (size_t)hk * T * 64;
    const ushort* Vb = Vt + (size_t)hk * 64 * T;

    const int srow = l >> 3;                   // 0..7
    const int sc   = ((l & 7) ^ srow) * 8;     // swizzled global chunk offset
    const int swz  = lr & 7;
    const int tw = w >> 1;                     // staged tile: 0=Ke 1=Ko 2=Ve 3=Vo
    const int half4 = (w & 1) * 4;             // seg base within tile
    f32x4 zero = {0.f, 0.f, 0.f, 0.f};

#define ASTAGE(ss, nb) { \
    const int ke_ = (ss) * 128; \
    _Pragma("unroll") \
    for (int i_ = 0; i_ < 4; ++i_) { \
        const int segq_ = half4 + i_; \
        const int grow_ = segq_ * 8 + srow; \
        if (tw == 0)      gld_lds16(Kb + (size_t)(ke_ + grow_) * 64 + sc,      &Ks[nb][0][segq_ * 512]); \
        else if (tw == 1) gld_lds16(Kb + (size_t)(ke_ + 64 + grow_) * 64 + sc, &Ks[nb][1][segq_ * 512]); \
        else if (tw == 2) gld_lds16(Vb + (size_t)grow_ * T + ke_ + sc,         &Vs[nb][0][segq_ * 512]); \
        else              gld_lds16(Vb + (size_t)grow_ * T + ke_ + 64 + sc,    &Vs[nb][1][segq_ * 512]); \
    } }

    for (int phase = 0; phase < 2; ++phase) {
        const int qt = phase == 0 ? (15 - (int)blockIdx.x) : (int)blockIdx.x;
        const int qbase = qt * 128;
        const int diag_rg = 2 * qt + (rg >> 1);    // last (masked) k-tile for this row group
        const int qrow0 = qbase + rg * 32 + lr;
        const int nst = qt + 1;                    // super-steps of 128 keys

        // Q B-fragments (both parity waves of a row group load the same rows)
        short8 qf[2][2];
#pragma unroll
        for (int ni = 0; ni < 2; ++ni)
#pragma unroll
            for (int ks = 0; ks < 2; ++ks)
                qf[ni][ks] = *(const short8*)(Q + ((size_t)h * T + qbase + rg * 32 + ni * 16 + lr) * 64 + ks * 32 + quad * 8);

        f32x4 oacc[2][4];
#pragma unroll
        for (int ni = 0; ni < 2; ++ni)
#pragma unroll
            for (int dj = 0; dj < 4; ++dj) oacc[ni][dj] = zero;
        float lsum[2] = {0.f, 0.f};

        ASTAGE(0, 0);

        for (int st = 0; st < nst; ++st) {
            const int b = st & 1;
            __syncthreads();
            if (st + 1 < nst) ASTAGE(st + 1, b ^ 1);

            const int kt = 2 * st + pw;
            if (kt <= diag_rg) {
                const int k0 = kt * 64;
                const ushort* KsB = &Ks[b][pw][0];
                const ushort* VsB = &Vs[b][pw][0];

                // S^T = K @ Q^T
                f32x4 s[4][2];
#pragma unroll
                for (int mi = 0; mi < 4; ++mi)
#pragma unroll
                    for (int ni = 0; ni < 2; ++ni) s[mi][ni] = zero;
#pragma unroll
                for (int ks = 0; ks < 2; ++ks)
#pragma unroll
                    for (int mi = 0; mi < 4; ++mi) {
                        short8 kf = *(const short8*)&KsB[(mi * 16 + lr) * 64 + ((4 * ks + quad) ^ swz) * 8];
                        s[mi][0] = MFMA16(kf, qf[0][ks], s[mi][0]);
                        s[mi][1] = MFMA16(kf, qf[1][ks], s[mi][1]);
                    }

                // exp (+ diagonal mask) -> Ps (ushort4 = 4 consecutive keys)
                const bool masked = (kt == diag_rg);
#pragma unroll
                for (int mi = 0; mi < 4; ++mi)
#pragma unroll
                    for (int ni = 0; ni < 2; ++ni) {
                        float pv[4];
#pragma unroll
                        for (int r = 0; r < 4; ++r) {
                            float p = __expf(s[mi][ni][r] * 0.125f);
                            if (masked && (k0 + mi * 16 + quad * 4 + r > qrow0 + ni * 16)) p = 0.f;
                            lsum[ni] += p;
                            pv[r] = p;
                        }
                        ushort4 pk;
                        pk.x = f2bf(pv[0]); pk.y = f2bf(pv[1]); pk.z = f2bf(pv[2]); pk.w = f2bf(pv[3]);
                        *(ushort4*)&Ps[w][(ni * 16 + lr) * 72 + mi * 16 + quad * 4] = pk;
                    }

                // O += P @ V^T
#pragma unroll
                for (int ks2 = 0; ks2 < 2; ++ks2) {
                    short8 pf0 = *(const short8*)&Ps[w][lr * 72 + ks2 * 32 + quad * 8];
                    short8 pf1 = *(const short8*)&Ps[w][(16 + lr) * 72 + ks2 * 32 + quad * 8];
#pragma unroll
                    for (int dj = 0; dj < 4; ++dj) {
                        short8 vf = *(const short8*)&VsB[(dj * 16 + lr) * 64 + ((4 * ks2 + quad) ^ swz) * 8];
                        oacc[0][dj] = MFMA16(pf0, vf, oacc[0][dj]);
                        oacc[1][dj] = MFMA16(pf1, vf, oacc[1][dj]);
                    }
                }
            }
        }

        // per-wave denominator reduction (sum over quads -> per-qrow partial)
        float vred[2];
#pragma unroll
        for (int ni = 0; ni < 2; ++ni) {
            float v = lsum[ni];
            v += __shfl_xor(v, 16, 64);
            v += __shfl_xor(v, 32, 64);
            vred[ni] = v;
        }

        // parity merge: pw1 writes partials into Ps-as-float, pw0 combines
        __syncthreads();
        if (pw == 1) {
#pragma unroll
            for (int ni = 0; ni < 2; ++ni)
#pragma unroll
                for (int dj = 0; dj < 4; ++dj)
#pragma unroll
                    for (int r = 0; r < 4; ++r)
                        mrg[rg * 2048 + ((ni * 4 + dj) * 4 + r) * 64 + l] = oacc[ni][dj][r];
            if (quad == 0) {
#pragma unroll
                for (int ni = 0; ni < 2; ++ni)
                    mrg[8192 + rg * 32 + ni * 16 + lr] = vred[ni];
            }
        }
        __syncthreads();
        if (pw == 0) {
            float inv[2][4];
#pragma unroll
            for (int ni = 0; ni < 2; ++ni) {
                float vtot = vred[ni] + mrg[8192 + rg * 32 + ni * 16 + lr];
#pragma unroll
                for (int r = 0; r < 4; ++r)
                    inv[ni][r] = 1.f / __shfl(vtot, quad * 4 + r, 64);
            }
#pragma unroll
            for (int ni = 0; ni < 2; ++ni)
#pragma unroll
                for (int dj = 0; dj < 4; ++dj) {
                    int col = h * 64 + dj * 16 + lr;
#pragma unroll
                    for (int r = 0; r < 4; ++r) {
                        float o = oacc[ni][dj][r] + mrg[rg * 2048 + ((ni * 4 + dj) * 4 + r) * 64 + l];
                        int row = qbase + rg * 32 + ni * 16 + quad * 4 + r;
                        ctx[(size_t)row * 2048 + col] = f2bf(o * inv[ni][r]);
                    }
                }
        }
        __syncthreads();   // protect mrg/Ps before next phase's first compute
    }
#undef ASTAGE
}

// ---------------------------------------------------------------------------
extern "C" void kernel_launch(void* const* d_in, const int* in_sizes, int n_in,
                              void* d_out, int out_size, void* d_ws, size_t ws_size,
                              hipStream_t stream) {
    const float* x  = (const float*)d_in[0];
    const float* Wq = (const float*)d_in[1];
    const float* Wk = (const float*)d_in[2];
    const float* Wv = (const float*)d_in[3];
    const float* Wo = (const float*)d_in[4];
    const int* start_pos = (const int*)d_in[5];
    float* out = (float*)d_out;

    const int T = T_SEQ, D = D_MODEL;
    const int KV = N_KV * HEAD_DIM;  // 512

    char* w = (char*)d_ws;
    float* cosT = (float*)w;            w += (size_t)32 * T * 4;
    float* sinT = (float*)w;            w += (size_t)32 * T * 4;
    ushort* xbf  = (ushort*)w;          w += (size_t)T * D * 2;     // aliased: ctx
    ushort* wqbf = (ushort*)w;          w += (size_t)D * D * 2;
    ushort* wkbf = (ushort*)w;          w += (size_t)KV * D * 2;
    ushort* wvbf = (ushort*)w;          w += (size_t)KV * D * 2;
    ushort* wobf = (ushort*)w;          w += (size_t)D * D * 2;
    ushort* qbf  = (ushort*)w;          w += (size_t)N_HEADS * T * 64 * 2;
    ushort* kbf  = (ushort*)w;          w += (size_t)N_KV * T * 64 * 2;
    ushort* vtbf = (ushort*)w;          w += (size_t)N_KV * 64 * T * 2;
    ushort* ctxbf = xbf;  // x fully consumed by gemm_qkv before attn writes ctx

    rope_tables_kernel<<<dim3(T), dim3(32), 0, stream>>>(cosT, sinT, start_pos, T);

    cast_all_kernel<<<dim3(14336), dim3(256), 0, stream>>>(x, Wq, Wk, Wv, Wo,
                                                           xbf, wqbf, wkbf, wvbf, wobf);

    gemm_qkv<<<dim3(T / 64, (D + 2 * KV) / 128), dim3(256), 0, stream>>>(
        xbf, wqbf, wkbf, wvbf, qbf, kbf, vtbf, cosT, sinT, T, D);

    attn_mfma<<<dim3(8, N_HEADS), dim3(512), 0, stream>>>(qbf, kbf, vtbf, ctxbf, T);

    gemm_bt_f32<<<dim3(T / 64, D / 128), dim3(256), 0, stream>>>(ctxbf, wobf, out, T, D, D);
}

// Round 8
// 212.959 us; speedup vs baseline: 1.2721x; 1.0267x over previous
//
#include <hip/hip_runtime.h>
#include <math.h>

#define T_SEQ 2048
#define D_MODEL 2048
#define HEAD_DIM 64
#define N_HEADS 32
#define N_KV 8

using short8 = __attribute__((ext_vector_type(8))) short;
using f32x4  = __attribute__((ext_vector_type(4))) float;

#define MFMA16(a, b, c) __builtin_amdgcn_mfma_f32_16x16x32_bf16(a, b, c, 0, 0, 0)

__device__ __forceinline__ unsigned short f2bf(float f) {
    unsigned int u = __builtin_bit_cast(unsigned int, f);
    u += 0x7fff + ((u >> 16) & 1);
    return (unsigned short)(u >> 16);
}
__device__ __forceinline__ void gld_lds16(const ushort* g, ushort* l) {
    __builtin_amdgcn_global_load_lds((const __attribute__((address_space(1))) void*)g,
                                     (__attribute__((address_space(3))) void*)l, 16, 0, 0);
}

// ---------------------------------------------------------------------------
// RoPE tables (llama3 scaling), fp32, transposed [i][T]
// ---------------------------------------------------------------------------
__global__ void rope_tables_kernel(float* __restrict__ cosT, float* __restrict__ sinT,
                                   const int* __restrict__ start_pos, int T) {
    int t = blockIdx.x;
    int i = threadIdx.x;  // 0..31
    float pos = (float)(start_pos[0] + t);
    float expo = (float)i / 32.0f;
    float inv_freq = 1.0f / powf(500000.0f, expo);
    const float two_pi = 6.283185307179586f;
    float wavelen = two_pi / inv_freq;
    const float low_wl = 8192.0f;
    const float high_wl = 2048.0f;
    float inv;
    if (wavelen > low_wl) {
        inv = inv_freq / 32.0f;
    } else if (wavelen < high_wl) {
        inv = inv_freq;
    } else {
        float smooth = (8192.0f / wavelen - 1.0f) / 3.0f;
        inv = (1.0f - smooth) * (inv_freq / 32.0f) + smooth * inv_freq;
    }
    float ang = pos * inv;
    cosT[i * T + t] = cosf(ang);
    sinT[i * T + t] = sinf(ang);
}

// ---------------------------------------------------------------------------
// One cast kernel for all five fp32->bf16 conversions (float4 granules)
// ---------------------------------------------------------------------------
__global__ __launch_bounds__(256) void cast_all_kernel(
    const float* __restrict__ x, const float* __restrict__ wq,
    const float* __restrict__ wk, const float* __restrict__ wv,
    const float* __restrict__ wo,
    ushort* __restrict__ xb, ushort* __restrict__ wqb,
    ushort* __restrict__ wkb, ushort* __restrict__ wvb, ushort* __restrict__ wob) {
    int i = blockIdx.x * 256 + threadIdx.x;
    const float* src; ushort* dst; int off;
    if (i < 1048576)      { src = x;  dst = xb;  off = i; }
    else if (i < 2097152) { src = wq; dst = wqb; off = i - 1048576; }
    else if (i < 2359296) { src = wk; dst = wkb; off = i - 2097152; }
    else if (i < 2621440) { src = wv; dst = wvb; off = i - 2359296; }
    else                  { src = wo; dst = wob; off = i - 2621440; }
    float4 v = ((const float4*)src)[off];
    ushort4 o;
    o.x = f2bf(v.x); o.y = f2bf(v.y); o.z = f2bf(v.z); o.w = f2bf(v.w);
    ((ushort4*)dst)[off] = o;
}

// ---------------------------------------------------------------------------
// Fused QKV GEMM + RoPE epilogue. 64x128 tile, BK=64 as 2x BK=32 sub-tiles
// per barrier, dbuf, XOR-swizzled. Grid 32 x 24 = 768 blocks (3/CU).
// grid.y: 0..15 Q, 16..19 K, 20..23 V(transposed)
// ---------------------------------------------------------------------------
__global__ __launch_bounds__(256) void gemm_qkv(
    const ushort* __restrict__ X, const ushort* __restrict__ Wqb,
    const ushort* __restrict__ Wkb, const ushort* __restrict__ Wvb,
    ushort* __restrict__ Qo, ushort* __restrict__ Ko, ushort* __restrict__ Vto,
    const float* __restrict__ cosT, const float* __restrict__ sinT,
    int T, int D) {
    __shared__ __align__(16) ushort As[2][2][2048];   // [buf][sub][64x32]
    __shared__ __align__(16) ushort Bs[2][2][4096];   // [buf][sub][128x32]
    const int tid = threadIdx.x;
    const int w = tid >> 6, l = tid & 63;
    const int m0 = blockIdx.x * 64;
    const int n0g = blockIdx.y * 128;

    const ushort* B;
    ushort* Cout;
    int n0, doRope;
    if (n0g < 2048)      { B = Wqb + (size_t)n0g * D;          Cout = Qo;  n0 = n0g;        doRope = 1; }
    else if (n0g < 2560) { B = Wkb + (size_t)(n0g - 2048) * D; Cout = Ko;  n0 = n0g - 2048; doRope = 1; }
    else                 { B = Wvb + (size_t)(n0g - 2560) * D; Cout = Vto; n0 = n0g - 2560; doRope = 0; }

    const int wm = (w >> 1) * 32, wn = (w & 1) * 64;
    const int lr = l & 15;
    const int quad = l >> 4;

    f32x4 zero = {0.f, 0.f, 0.f, 0.f};
    f32x4 acc[2][4];
#pragma unroll
    for (int i = 0; i < 2; ++i)
#pragma unroll
        for (int j = 0; j < 4; ++j) acc[i][j] = zero;

    const int srow = l >> 2;                       // 0..15
    const int scg  = ((l & 3) ^ (srow & 3)) * 8;   // swizzled global chunk
    const ushort* Ag  = X + (size_t)(m0 + 16 * w + srow) * D + scg;
    const ushort* Bg0 = B + (size_t)(16 * (2 * w) + srow) * D + scg;
    const ushort* Bg1 = B + (size_t)(16 * (2 * w + 1) + srow) * D + scg;

#define GSTAGE(k0v, nb) { \
    gld_lds16(Ag  + (k0v),      &As[nb][0][w * 512]); \
    gld_lds16(Ag  + (k0v) + 32, &As[nb][1][w * 512]); \
    gld_lds16(Bg0 + (k0v),      &Bs[nb][0][(2 * w) * 512]); \
    gld_lds16(Bg0 + (k0v) + 32, &Bs[nb][1][(2 * w) * 512]); \
    gld_lds16(Bg1 + (k0v),      &Bs[nb][0][(2 * w + 1) * 512]); \
    gld_lds16(Bg1 + (k0v) + 32, &Bs[nb][1][(2 * w + 1) * 512]); }

    GSTAGE(0, 0);

    const int rsw = (quad ^ (lr & 3)) * 8;
    for (int k0 = 0; k0 < D; k0 += 64) {
        const int b = (k0 >> 6) & 1;
        __syncthreads();
        if (k0 + 64 < D) GSTAGE(k0 + 64, b ^ 1);
#pragma unroll
        for (int sub = 0; sub < 2; ++sub) {
            short8 af[2], bf[4];
#pragma unroll
            for (int i = 0; i < 2; ++i) af[i] = *(const short8*)&As[b][sub][(wm + i * 16 + lr) * 32 + rsw];
#pragma unroll
            for (int j = 0; j < 4; ++j) bf[j] = *(const short8*)&Bs[b][sub][(wn + j * 16 + lr) * 32 + rsw];
#pragma unroll
            for (int i = 0; i < 2; ++i)
#pragma unroll
                for (int j = 0; j < 4; ++j)
                    acc[i][j] = MFMA16(af[i], bf[j], acc[i][j]);
        }
    }
#undef GSTAGE

    const int mbase = m0 + wm + quad * 4;
    if (doRope) {
#pragma unroll
        for (int i = 0; i < 2; ++i) {
            int trow = mbase + i * 16;
#pragma unroll
            for (int j = 0; j < 2; ++j) {
                int i1 = lr + j * 16;
                float4 c4 = *(const float4*)&cosT[(size_t)i1 * T + trow];
                float4 s4 = *(const float4*)&sinT[(size_t)i1 * T + trow];
                int n1 = n0 + wn + lr + j * 16;
                int n2 = n1 + 32;
                size_t b1 = (size_t)(n1 >> 6) * ((size_t)T * 64) + (size_t)(n1 & 63);
                size_t b2 = (size_t)(n2 >> 6) * ((size_t)T * 64) + (size_t)(n2 & 63);
                float cs[4] = {c4.x, c4.y, c4.z, c4.w};
                float sn[4] = {s4.x, s4.y, s4.z, s4.w};
#pragma unroll
                for (int r = 0; r < 4; ++r) {
                    float x1 = acc[i][j][r], x2 = acc[i][j + 2][r];
                    Cout[b1 + (size_t)(trow + r) * 64] = f2bf(x1 * cs[r] - x2 * sn[r]);
                    Cout[b2 + (size_t)(trow + r) * 64] = f2bf(x2 * cs[r] + x1 * sn[r]);
                }
            }
        }
    } else {
#pragma unroll
        for (int i = 0; i < 2; ++i)
#pragma unroll
            for (int j = 0; j < 4; ++j) {
                int n = n0 + wn + lr + j * 16;
                int m = mbase + i * 16;
                ushort4 o;
                o.x = f2bf(acc[i][j][0]); o.y = f2bf(acc[i][j][1]);
                o.z = f2bf(acc[i][j][2]); o.w = f2bf(acc[i][j][3]);
                *(ushort4*)&Vto[(size_t)n * T + m] = o;
            }
    }
}

// ---------------------------------------------------------------------------
// Output projection GEMM (C fp32), same BK=64 dual-sub-tile core
// ---------------------------------------------------------------------------
__global__ __launch_bounds__(256) void gemm_bt_f32(const ushort* __restrict__ A,
                                                   const ushort* __restrict__ B,
                                                   float* __restrict__ C,
                                                   int M, int N, int K) {
    __shared__ __align__(16) ushort As[2][2][2048];
    __shared__ __align__(16) ushort Bs[2][2][4096];
    const int tid = threadIdx.x;
    const int w = tid >> 6, l = tid & 63;
    const int m0 = blockIdx.x * 64, n0 = blockIdx.y * 128;
    const int wm = (w >> 1) * 32, wn = (w & 1) * 64;
    const int lr = l & 15;
    const int quad = l >> 4;

    f32x4 zero = {0.f, 0.f, 0.f, 0.f};
    f32x4 acc[2][4];
#pragma unroll
    for (int i = 0; i < 2; ++i)
#pragma unroll
        for (int j = 0; j < 4; ++j) acc[i][j] = zero;

    const int srow = l >> 2;
    const int scg  = ((l & 3) ^ (srow & 3)) * 8;
    const ushort* Ag  = A + (size_t)(m0 + 16 * w + srow) * K + scg;
    const ushort* Bg0 = B + (size_t)(n0 + 16 * (2 * w) + srow) * K + scg;
    const ushort* Bg1 = B + (size_t)(n0 + 16 * (2 * w + 1) + srow) * K + scg;

#define GSTAGE(k0v, nb) { \
    gld_lds16(Ag  + (k0v),      &As[nb][0][w * 512]); \
    gld_lds16(Ag  + (k0v) + 32, &As[nb][1][w * 512]); \
    gld_lds16(Bg0 + (k0v),      &Bs[nb][0][(2 * w) * 512]); \
    gld_lds16(Bg0 + (k0v) + 32, &Bs[nb][1][(2 * w) * 512]); \
    gld_lds16(Bg1 + (k0v),      &Bs[nb][0][(2 * w + 1) * 512]); \
    gld_lds16(Bg1 + (k0v) + 32, &Bs[nb][1][(2 * w + 1) * 512]); }

    GSTAGE(0, 0);

    const int rsw = (quad ^ (lr & 3)) * 8;
    for (int k0 = 0; k0 < K; k0 += 64) {
        const int b = (k0 >> 6) & 1;
        __syncthreads();
        if (k0 + 64 < K) GSTAGE(k0 + 64, b ^ 1);
#pragma unroll
        for (int sub = 0; sub < 2; ++sub) {
            short8 af[2], bf[4];
#pragma unroll
            for (int i = 0; i < 2; ++i) af[i] = *(const short8*)&As[b][sub][(wm + i * 16 + lr) * 32 + rsw];
#pragma unroll
            for (int j = 0; j < 4; ++j) bf[j] = *(const short8*)&Bs[b][sub][(wn + j * 16 + lr) * 32 + rsw];
#pragma unroll
            for (int i = 0; i < 2; ++i)
#pragma unroll
                for (int j = 0; j < 4; ++j)
                    acc[i][j] = MFMA16(af[i], bf[j], acc[i][j]);
        }
    }
#undef GSTAGE

    const int mbase = m0 + wm + quad * 4;
    const int nbase = n0 + wn + lr;
#pragma unroll
    for (int i = 0; i < 2; ++i)
#pragma unroll
        for (int j = 0; j < 4; ++j)
#pragma unroll
            for (int r = 0; r < 4; ++r)
                C[(size_t)(mbase + i * 16 + r) * N + (nbase + j * 16)] = acc[i][j][r];
}

// ---------------------------------------------------------------------------
// Flash attention: 64-row q-tiles, 4 waves x 16 rows, grid (16,32) = 512
// blocks = 2/CU (cross-block barrier hiding). Block handles q-tiles 31-bx
// then bx -> 33 k-tile steps, uniform. S^T = K@Q^T (Q in regs), XOR-swizzled
// dbuf K/V (32 KB), Ps stride 72 (9.2 KB) -> 41 KB LDS total.
// R8 fix: prologue V staging rows now match the in-loop form (8*si+srow) —
// R7 staged dims 0..15 for every wave (the correctness bug).
// ---------------------------------------------------------------------------
__global__ __launch_bounds__(256) void attn_mfma(const ushort* __restrict__ Q,
                                                 const ushort* __restrict__ K,
                                                 const ushort* __restrict__ Vt,
                                                 ushort* __restrict__ ctx, int T) {
    __shared__ __align__(16) ushort Ks[2][4096];   // [key64][dim64] swizzled
    __shared__ __align__(16) ushort Vs[2][4096];   // [dim64][key64] swizzled
    __shared__ __align__(16) ushort Ps[4][1152];   // per-wave [qrow16][key64] stride 72
    const int tid = threadIdx.x, w = tid >> 6, l = tid & 63;
    const int lr = l & 15, quad = l >> 4;
    const int h = blockIdx.y, hk = h >> 2;
    const ushort* Kb = K + (size_t)hk * T * 64;
    const ushort* Vb = Vt + (size_t)hk * 64 * T;

    const int srow = l >> 3;                    // 0..7
    const int sc   = ((l & 7) ^ srow) * 8;      // swizzled global chunk offset
    const int si0 = 2 * w, si1 = 2 * w + 1;
    const int swz = lr & 7;
    f32x4 zero = {0.f, 0.f, 0.f, 0.f};

    for (int phase = 0; phase < 2; ++phase) {
        const int qt = phase == 0 ? (31 - (int)blockIdx.x) : (int)blockIdx.x;
        const int qbase = qt * 64;
        const int qrow_abs = qbase + w * 16 + lr;   // this lane's q row (exp stage)
        const int ntiles = qt + 1;

        // Q B-fragments in registers for this phase
        short8 qf[2];
#pragma unroll
        for (int ks = 0; ks < 2; ++ks)
            qf[ks] = *(const short8*)(Q + ((size_t)h * T + qbase + w * 16 + lr) * 64 + ks * 32 + quad * 8);

        f32x4 oacc[4];
#pragma unroll
        for (int dj = 0; dj < 4; ++dj) oacc[dj] = zero;
        float lsum = 0.f;

        // prologue: stage tile 0 into buf 0 (identical row math to in-loop staging)
        gld_lds16(Kb + (size_t)(8 * si0 + srow) * 64 + sc, &Ks[0][si0 * 512]);
        gld_lds16(Kb + (size_t)(8 * si1 + srow) * 64 + sc, &Ks[0][si1 * 512]);
        gld_lds16(Vb + (size_t)(8 * si0 + srow) * T + sc, &Vs[0][si0 * 512]);
        gld_lds16(Vb + (size_t)(8 * si1 + srow) * T + sc, &Vs[0][si1 * 512]);

        for (int kt = 0; kt < ntiles; ++kt) {
            const int b = kt & 1;
            __syncthreads();
            if (kt + 1 < ntiles) {
                const int k0n = (kt + 1) * 64;
                gld_lds16(Kb + (size_t)(k0n + 8 * si0 + srow) * 64 + sc, &Ks[b ^ 1][si0 * 512]);
                gld_lds16(Kb + (size_t)(k0n + 8 * si1 + srow) * 64 + sc, &Ks[b ^ 1][si1 * 512]);
                gld_lds16(Vb + (size_t)(8 * si0 + srow) * T + k0n + sc, &Vs[b ^ 1][si0 * 512]);
                gld_lds16(Vb + (size_t)(8 * si1 + srow) * T + k0n + sc, &Vs[b ^ 1][si1 * 512]);
            }
            const int k0 = kt * 64;

            // S^T = K @ Q^T : D[m=key][n=qrow(16)]
            f32x4 s[4];
#pragma unroll
            for (int mi = 0; mi < 4; ++mi) s[mi] = zero;
#pragma unroll
            for (int ks = 0; ks < 2; ++ks)
#pragma unroll
                for (int mi = 0; mi < 4; ++mi) {
                    short8 kf = *(const short8*)&Ks[b][(mi * 16 + lr) * 64 + ((4 * ks + quad) ^ swz) * 8];
                    s[mi] = MFMA16(kf, qf[ks], s[mi]);
                }

            // exp (+ mask on diagonal tile) -> Ps (ushort4 = 4 consecutive keys)
            const bool masked = (kt == qt);
#pragma unroll
            for (int mi = 0; mi < 4; ++mi) {
                float pv[4];
#pragma unroll
                for (int r = 0; r < 4; ++r) {
                    float p = __expf(s[mi][r] * 0.125f);
                    if (masked && (k0 + mi * 16 + quad * 4 + r > qrow_abs)) p = 0.f;
                    lsum += p;
                    pv[r] = p;
                }
                ushort4 pk;
                pk.x = f2bf(pv[0]); pk.y = f2bf(pv[1]); pk.z = f2bf(pv[2]); pk.w = f2bf(pv[3]);
                *(ushort4*)&Ps[w][lr * 72 + mi * 16 + quad * 4] = pk;
            }

            // O += P @ V^T : A = P[qrow][key] rows, B = Vt[dim][key] rows
#pragma unroll
            for (int ks2 = 0; ks2 < 2; ++ks2) {
                short8 pf = *(const short8*)&Ps[w][lr * 72 + ks2 * 32 + quad * 8];
#pragma unroll
                for (int dj = 0; dj < 4; ++dj) {
                    short8 vf = *(const short8*)&Vs[b][(dj * 16 + lr) * 64 + ((4 * ks2 + quad) ^ swz) * 8];
                    oacc[dj] = MFMA16(pf, vf, oacc[dj]);
                }
            }
        }

        // denominator: reduce over quads (keys); lane (q,lr) holds partial for qrow lr
        float v = lsum;
        v += __shfl_xor(v, 16, 64);
        v += __shfl_xor(v, 32, 64);
        float invr[4];
#pragma unroll
        for (int r = 0; r < 4; ++r)
            invr[r] = 1.f / __shfl(v, quad * 4 + r, 64);

        // write ctx [t][2048] bf16; O C-layout: row=quad*4+r (qrow), col=lr (dim)
#pragma unroll
        for (int dj = 0; dj < 4; ++dj) {
            int col = h * 64 + dj * 16 + lr;
#pragma unroll
            for (int r = 0; r < 4; ++r) {
                int row = qbase + w * 16 + quad * 4 + r;
                ctx[(size_t)row * 2048 + col] = f2bf(oacc[dj][r] * invr[r]);
            }
        }
        __syncthreads();   // protect LDS buffers before next phase's prologue staging
    }
}

// ---------------------------------------------------------------------------
extern "C" void kernel_launch(void* const* d_in, const int* in_sizes, int n_in,
                              void* d_out, int out_size, void* d_ws, size_t ws_size,
                              hipStream_t stream) {
    const float* x  = (const float*)d_in[0];
    const float* Wq = (const float*)d_in[1];
    const float* Wk = (const float*)d_in[2];
    const float* Wv = (const float*)d_in[3];
    const float* Wo = (const float*)d_in[4];
    const int* start_pos = (const int*)d_in[5];
    float* out = (float*)d_out;

    const int T = T_SEQ, D = D_MODEL;
    const int KV = N_KV * HEAD_DIM;  // 512

    char* w = (char*)d_ws;
    float* cosT = (float*)w;            w += (size_t)32 * T * 4;
    float* sinT = (float*)w;            w += (size_t)32 * T * 4;
    ushort* xbf  = (ushort*)w;          w += (size_t)T * D * 2;     // aliased: ctx
    ushort* wqbf = (ushort*)w;          w += (size_t)D * D * 2;
    ushort* wkbf = (ushort*)w;          w += (size_t)KV * D * 2;
    ushort* wvbf = (ushort*)w;          w += (size_t)KV * D * 2;
    ushort* wobf = (ushort*)w;          w += (size_t)D * D * 2;
    ushort* qbf  = (ushort*)w;          w += (size_t)N_HEADS * T * 64 * 2;
    ushort* kbf  = (ushort*)w;          w += (size_t)N_KV * T * 64 * 2;
    ushort* vtbf = (ushort*)w;          w += (size_t)N_KV * 64 * T * 2;
    ushort* ctxbf = xbf;  // x fully consumed by gemm_qkv before attn writes ctx

    rope_tables_kernel<<<dim3(T), dim3(32), 0, stream>>>(cosT, sinT, start_pos, T);

    cast_all_kernel<<<dim3(14336), dim3(256), 0, stream>>>(x, Wq, Wk, Wv, Wo,
                                                           xbf, wqbf, wkbf, wvbf, wobf);

    gemm_qkv<<<dim3(T / 64, (D + 2 * KV) / 128), dim3(256), 0, stream>>>(
        xbf, wqbf, wkbf, wvbf, qbf, kbf, vtbf, cosT, sinT, T, D);

    attn_mfma<<<dim3(16, N_HEADS), dim3(256), 0, stream>>>(qbf, kbf, vtbf, ctxbf, T);

    gemm_bt_f32<<<dim3(T / 64, D / 128), dim3(256), 0, stream>>>(ctxbf, wobf, out, T, D, D);
}